// Round 1
// baseline (486.366 us; speedup 1.0000x reference)
//
#include <hip/hip_runtime.h>

// GNNModel fused via MFMA. R13 = R12 + fragment-layout LDS for h (conflict-free
// sequential ds_read_b128 A-frag reads), double-buffered hf (one barrier per
// layer, 4 total vs 7), persistent bA registers (7 frags; the 2 cross-batch
// AmatT tiles are exactly zero and skipped), tail FMA chain split 4-way,
// hoisted tail scalar loads. Adjacency bit-exact fp32; A = mask + eye (diag 2).

typedef _Float16 half4v __attribute__((ext_vector_type(4)));
typedef _Float16 half8v __attribute__((ext_vector_type(8)));
typedef float    float4v __attribute__((ext_vector_type(4)));

constexpr int PP = 12, DIN = 32, H = 128, HO = 64, DOUT = 3, NL = 3;
constexpr int NB = 4, ROWS = NB * PP;   // 48 rows per block (4 batches x 12)
constexpr int AP2 = 72;                 // AmatT stride (halves)

// ws layout in halves: WinT[128][32] @0 ; WgT[3][128][128] @4096 ; W1T[64][128] @53248
constexpr int WS_WG = 4096, WS_W1 = 53248, WS_TOT = 61440;

__global__ __launch_bounds__(256)
void prep_weights(const float* __restrict__ W_in, const float* __restrict__ W_gcn,
                  const float* __restrict__ W_out1, _Float16* __restrict__ ws)
{
    int e = blockIdx.x * 256 + threadIdx.x;
    if (e < WS_WG) {                        // WinT[n][k] = W_in[k][n]
        int n = e >> 5, k = e & 31;
        ws[e] = (_Float16)W_in[k * H + n];
    } else if (e < WS_W1) {                 // WgT[l][n][k] = W_gcn[l][k][n]
        int e2 = e - WS_WG;
        int l = e2 >> 14, r = e2 & 16383, n = r >> 7, k = r & 127;
        ws[e] = (_Float16)W_gcn[l * (H * H) + k * H + n];
    } else if (e < WS_TOT) {                // W1T[o][k] = W_out1[k][o]
        int e3 = e - WS_W1;
        int o = e3 >> 7, k = e3 & 127;
        ws[e] = (_Float16)W_out1[k * HO + o];
    }
}

__device__ inline half4v pk4(float a, float b, float c, float d) {
    half4v r; r[0] = (_Float16)a; r[1] = (_Float16)b; r[2] = (_Float16)c; r[3] = (_Float16)d;
    return r;
}

__global__ __launch_bounds__(256, 4)
void gnn_mfma(const float* __restrict__ x,
              const float* __restrict__ b_in,
              const float* __restrict__ b_gcn,
              const float* __restrict__ b_out1,
              const float* __restrict__ W_out2,
              const float* __restrict__ b_out2,
              const _Float16* __restrict__ ws,
              float* __restrict__ out)
{
    // h in MFMA fragment layout, double-buffered:
    //   hf[buf][mt*4+kt][lane*8+j] = h[16*mt + (lane&15)][32*kt + 8*(lane>>4) + j]
    // t-phase A-frag read = ds_read_b128 at lane*16 (sequential, conflict-free).
    __shared__ __align__(16) _Float16 hf[2][12][512];  // 24 KB
    __shared__ __align__(16) char r3[ROWS * AP2 * 2];  // 6.75 KB: AmatT, later g_s
    _Float16 (*AmatT)[AP2] = (_Float16 (*)[AP2])r3;
    float (*g_s)[H] = (float (*)[H])r3;                // [4][128] fp32 (2 KB)

    const int tid  = threadIdx.x;
    const int lane = tid & 63, wave = tid >> 6;
    const int q = lane >> 4, qm = lane & 15;
    const int b0 = blockIdx.x * NB;
    const float* xblk = x + (size_t)b0 * (PP * DIN);

    // ---- issue x loads (lon + proj B-frag quads) ----
    float lon_own = 0.f;
    if (lane < PP) lon_own = xblk[(wave * PP + lane) * DIN];
    float4 xa[3], xb[3];
    #pragma unroll
    for (int nt = 0; nt < 3; ++nt) {
        const float* p = xblk + (16 * nt + qm) * DIN + 8 * q;
        xa[nt] = *(const float4*)p;
        xb[nt] = *(const float4*)(p + 4);
    }

    // ---- hoist tail scalar loads (L2-hot, tiny, removes serial latency from tail) ----
    const float bo1 = b_out1[lane];
    const float w20 = W_out2[lane * DOUT + 0];
    const float w21 = W_out2[lane * DOUT + 1];
    const float w22 = W_out2[lane * DOUT + 2];
    const float bo20 = b_out2[0], bo21 = b_out2[1], bo22 = b_out2[2];

    // ---- adjacency via shfl (bit-exact fp32 mask); wave w = batch w ----
    {
        float lonj[PP];
        #pragma unroll
        for (int j = 0; j < PP; ++j) lonj[j] = __shfl(lon_own, j, 64);
        float deg = 1.0f;                              // GCNConv's appended self-loop
        #pragma unroll
        for (int j = 0; j < PP; ++j) {
            float d = fabsf(lon_own - lonj[j]);
            d = fminf(d, 360.0f - d);
            deg += (d < 10.0f) ? 1.0f : 0.0f;          // diag: d=0 -> 1
        }
        float dinv_own = rsqrtf(fmaxf(deg, 1e-12f));
        float dj[PP];
        #pragma unroll
        for (int j = 0; j < PP; ++j) dj[j] = __shfl(dinv_own, j, 64);

        if (lane < PP) {
            const int n = wave * PP + lane;
            half8v z = {0, 0, 0, 0, 0, 0, 0, 0};
            #pragma unroll
            for (int c = 0; c < 48; c += 8) *(half8v*)&AmatT[n][c] = z;
            _Float16 vals[PP];
            #pragma unroll
            for (int j = 0; j < PP; ++j) {
                float d = fabsf(lon_own - lonj[j]);
                d = fminf(d, 360.0f - d);
                float a = (d < 10.0f) ? 1.0f : 0.0f;
                if (j == lane) a += 1.0f;              // A = mask + eye: diag = 2
                vals[j] = (_Float16)(a * dinv_own * dj[j]);
            }
            #pragma unroll
            for (int t4 = 0; t4 < 3; ++t4) {
                half4v v;
                v[0] = vals[4 * t4]; v[1] = vals[4 * t4 + 1];
                v[2] = vals[4 * t4 + 2]; v[3] = vals[4 * t4 + 3];
                *(half4v*)&AmatT[n][wave * PP + 4 * t4] = v;
            }
        }
    }

    // ---- proj: h0^T = WinT @ x^T -> hf[0] fragment layout ----
    {
        half8v bx[3];
        #pragma unroll
        for (int nt = 0; nt < 3; ++nt) {
            half8v h;
            h[0] = (_Float16)xa[nt].x; h[1] = (_Float16)xa[nt].y;
            h[2] = (_Float16)xa[nt].z; h[3] = (_Float16)xa[nt].w;
            h[4] = (_Float16)xb[nt].x; h[5] = (_Float16)xb[nt].y;
            h[6] = (_Float16)xb[nt].z; h[7] = (_Float16)xb[nt].w;
            bx[nt] = h;
        }
        #pragma unroll
        for (int mt2 = 0; mt2 < 2; ++mt2) {
            const int m = 32 * wave + 16 * mt2;
            half8v aw = *(const half8v*)&ws[(m + qm) * DIN + 8 * q];
            float4 bi = *(const float4*)&b_in[m + 4 * q];
            // element h[16*nt+qm][m+4q+r] -> frag [nt][kt=wave],
            // slot = qm + 16*((2*mt2+(q>>1))&3), half-offset (q&1)*4
            const int slot = qm + 16 * ((2 * mt2 + (q >> 1)) & 3);
            #pragma unroll
            for (int nt = 0; nt < 3; ++nt) {
                float4v c = {0.f, 0.f, 0.f, 0.f};
                c = __builtin_amdgcn_mfma_f32_16x16x32_f16(aw, bx[nt], c, 0, 0, 0);
                *(half4v*)&hf[0][nt * 4 + wave][slot * 8 + (q & 1) * 4] =
                    pk4(c[0] + bi.x, c[1] + bi.y, c[2] + bi.z, c[3] + bi.w);
            }
        }
    }
    __syncthreads();   // B1: hf[0] + AmatT complete

    const _Float16* WgT = ws + WS_WG;

    // ---- persistent Amat B-frags (live across all 3 layers; 7 x half4v = 14 VGPR)
    // bA[mt][nt] = AmatT[16*nt+qm][16*mt+4q]; tiles (mt,nt)=(2,0),(0,2) are
    // exactly zero (cross-batch blocks of the block-diagonal Ahat) -> skipped.
    const half4v bA00 = *(const half4v*)&AmatT[qm][4 * q];
    const half4v bA10 = *(const half4v*)&AmatT[qm][16 + 4 * q];
    const half4v bA01 = *(const half4v*)&AmatT[16 + qm][4 * q];
    const half4v bA11 = *(const half4v*)&AmatT[16 + qm][16 + 4 * q];
    const half4v bA21 = *(const half4v*)&AmatT[16 + qm][32 + 4 * q];
    const half4v bA12 = *(const half4v*)&AmatT[32 + qm][16 + 4 * q];
    const half4v bA22 = *(const half4v*)&AmatT[32 + qm][32 + 4 * q];

    // ---- GCN layers: read hf[l&1], write hf[(l&1)^1]; ONE barrier per layer ----
    #pragma unroll
    for (int l = 0; l < NL; ++l) {
        const int rb = l & 1, wb = rb ^ 1;
        const _Float16* Wl = WgT + l * (H * H);
        half8v bw[2][4];
        #pragma unroll
        for (int n2 = 0; n2 < 2; ++n2)
            #pragma unroll
            for (int kt = 0; kt < 4; ++kt)
                bw[n2][kt] = *(const half8v*)&Wl[(32 * wave + 16 * n2 + qm) * H + 32 * kt + 8 * q];
        const float4 bg0 = *(const float4*)&b_gcn[l * H + 32 * wave + 4 * q];
        const float4 bg1 = *(const float4*)&b_gcn[l * H + 32 * wave + 16 + 4 * q];

        // t = h @ Wl (K=32 MFMA; A-frags = sequential b128 reads, conflict-free)
        float4v c[3][2];
        #pragma unroll
        for (int mt = 0; mt < 3; ++mt) {
            c[mt][0] = (float4v){0.f, 0.f, 0.f, 0.f};
            c[mt][1] = (float4v){0.f, 0.f, 0.f, 0.f};
        }
        #pragma unroll
        for (int kt = 0; kt < 4; ++kt)
            #pragma unroll
            for (int mt = 0; mt < 3; ++mt) {
                half8v a = *(const half8v*)&hf[rb][mt * 4 + kt][lane * 8];
                c[mt][0] = __builtin_amdgcn_mfma_f32_16x16x32_f16(a, bw[0][kt], c[mt][0], 0, 0, 0);
                c[mt][1] = __builtin_amdgcn_mfma_f32_16x16x32_f16(a, bw[1][kt], c[mt][1], 0, 0, 0);
            }

        // pack t C-tiles -> mix A-frags (t^T), in-register (chaining identity)
        half4v ah[3][2];
        #pragma unroll
        for (int mt = 0; mt < 3; ++mt)
            #pragma unroll
            for (int n2 = 0; n2 < 2; ++n2)
                ah[mt][n2] = pk4(c[mt][n2][0], c[mt][n2][1], c[mt][n2][2], c[mt][n2][3]);

        // mix: h'^T = t^T @ Amat; writes go to the OTHER buffer -> no WAR barrier
        #pragma unroll
        for (int n2 = 0; n2 < 2; ++n2) {
            const float4 bg = n2 ? bg1 : bg0;
            const int slot = qm + 16 * ((2 * n2 + (q >> 1)) & 3);
            const int hoff = slot * 8 + (q & 1) * 4;

            float4v d0 = {0.f, 0.f, 0.f, 0.f};
            d0 = __builtin_amdgcn_mfma_f32_16x16x16f16(ah[0][n2], bA00, d0, 0, 0, 0);
            d0 = __builtin_amdgcn_mfma_f32_16x16x16f16(ah[1][n2], bA10, d0, 0, 0, 0);
            *(half4v*)&hf[wb][0 * 4 + wave][hoff] =
                pk4(fmaxf(d0[0] + bg.x, 0.f), fmaxf(d0[1] + bg.y, 0.f),
                    fmaxf(d0[2] + bg.z, 0.f), fmaxf(d0[3] + bg.w, 0.f));

            float4v d1 = {0.f, 0.f, 0.f, 0.f};
            d1 = __builtin_amdgcn_mfma_f32_16x16x16f16(ah[0][n2], bA01, d1, 0, 0, 0);
            d1 = __builtin_amdgcn_mfma_f32_16x16x16f16(ah[1][n2], bA11, d1, 0, 0, 0);
            d1 = __builtin_amdgcn_mfma_f32_16x16x16f16(ah[2][n2], bA21, d1, 0, 0, 0);
            *(half4v*)&hf[wb][1 * 4 + wave][hoff] =
                pk4(fmaxf(d1[0] + bg.x, 0.f), fmaxf(d1[1] + bg.y, 0.f),
                    fmaxf(d1[2] + bg.z, 0.f), fmaxf(d1[3] + bg.w, 0.f));

            float4v d2 = {0.f, 0.f, 0.f, 0.f};
            d2 = __builtin_amdgcn_mfma_f32_16x16x16f16(ah[1][n2], bA12, d2, 0, 0, 0);
            d2 = __builtin_amdgcn_mfma_f32_16x16x16f16(ah[2][n2], bA22, d2, 0, 0, 0);
            *(half4v*)&hf[wb][2 * 4 + wave][hoff] =
                pk4(fmaxf(d2[0] + bg.x, 0.f), fmaxf(d2[1] + bg.y, 0.f),
                    fmaxf(d2[2] + bg.z, 0.f), fmaxf(d2[3] + bg.w, 0.f));
        }
        __syncthreads();   // end of layer: RAW for next layer / pool
    }

    // ---- tail: wave w owns batch w; final h lives in hf[1] ----
    {
        float s0 = 0.f, s1 = 0.f, s0b = 0.f, s1b = 0.f;
        const int gq = (lane >> 3) & 3, gj = lane & 7, kt0 = lane >> 5;
        #pragma unroll
        for (int p = 0; p < PP; ++p) {
            const int row = wave * PP + p;
            const int off = ((row & 15) + 16 * gq) * 8 + gj;
            const int mt4 = (row >> 4) * 4;
            float v0 = (float)hf[1][mt4 + kt0][off];
            float v1 = (float)hf[1][mt4 + 2 + kt0][off];
            if (p & 1) { s0b += v0; s1b += v1; } else { s0 += v0; s1 += v1; }
        }
        // r3 alias: AmatT dead (bA frags live in registers since before layer 0)
        g_s[wave][lane]      = (s0 + s0b) * (1.0f / 12.0f);
        g_s[wave][lane + 64] = (s1 + s1b) * (1.0f / 12.0f);
    }
    float o1;
    {
        float a0 = bo1, a1 = 0.f, a2 = 0.f, a3 = 0.f;   // 4-way chain split
        const _Float16* wr = ws + WS_W1 + lane * H;
        #pragma unroll
        for (int kk = 0; kk < H / 8; ++kk) {
            half8v wv = *(const half8v*)&wr[8 * kk];
            const float* gg = &g_s[wave][8 * kk];
            a0 += gg[0] * (float)wv[0] + gg[1] * (float)wv[1];
            a1 += gg[2] * (float)wv[2] + gg[3] * (float)wv[3];
            a2 += gg[4] * (float)wv[4] + gg[5] * (float)wv[5];
            a3 += gg[6] * (float)wv[6] + gg[7] * (float)wv[7];
        }
        o1 = fmaxf((a0 + a1) + (a2 + a3), 0.f);
    }
    {
        float p0 = o1 * w20;
        float p1 = o1 * w21;
        float p2 = o1 * w22;
        #pragma unroll
        for (int off = 32; off > 0; off >>= 1) {
            p0 += __shfl_xor(p0, off, 64);
            p1 += __shfl_xor(p1, off, 64);
            p2 += __shfl_xor(p2, off, 64);
        }
        if (lane == 0) {
            float* o = out + (size_t)(b0 + wave) * DOUT;
            o[0] = p0 + bo20;
            o[1] = p1 + bo21;
            o[2] = p2 + bo22;
        }
    }
}

extern "C" void kernel_launch(void* const* d_in, const int* in_sizes, int n_in,
                              void* d_out, int out_size, void* d_ws, size_t ws_size,
                              hipStream_t stream) {
    const float* x      = (const float*)d_in[0];
    const float* W_in   = (const float*)d_in[1];
    const float* b_in   = (const float*)d_in[2];
    const float* W_gcn  = (const float*)d_in[3];
    const float* b_gcn  = (const float*)d_in[4];
    const float* W_out1 = (const float*)d_in[5];
    const float* b_out1 = (const float*)d_in[6];
    const float* W_out2 = (const float*)d_in[7];
    const float* b_out2 = (const float*)d_in[8];
    float* outp         = (float*)d_out;
    _Float16* wsh       = (_Float16*)d_ws;

    const int B = in_sizes[0] / (PP * DIN);        // 65536

    hipLaunchKernelGGL(prep_weights, dim3((WS_TOT + 255) / 256), dim3(256), 0, stream,
                       W_in, W_gcn, W_out1, wsh);
    hipLaunchKernelGGL(gnn_mfma, dim3(B / NB), dim3(256), 0, stream,
                       x, b_in, b_gcn, b_out1, W_out2, b_out2, wsh, outp);
}

// Round 2
// 398.403 us; speedup vs baseline: 1.2208x; 1.2208x over previous
//
#include <hip/hip_runtime.h>

// GNNModel fused via MFMA. R14 = fragment-layout hf (conflict-free t-phase
// reads, single buffer -> 19.2 KB LDS for occupancy) + layer-2 transposed mix
// (Ahat·t using the SAME persistent bA registers as A-frags; symmetric Ahat,
// A/B frag layouts identical) so the mean-pool is 3 in-lane adds + 2 shfl_xor
// -- no layer-2 hf store, no conflicted pool reads, no final RAW barrier.
// Tail out1 is one K=128 MFMA chain per wave (A=W1T, B=g via 4.3KB LDS);
// out2 = 12 FMA + xor-reduce + tiny cross-wave sum. Next-layer weight frags
// prefetch during mix (regs dead after t-phase). Adjacency bit-exact fp32.

typedef _Float16 half4v __attribute__((ext_vector_type(4)));
typedef _Float16 half8v __attribute__((ext_vector_type(8)));
typedef float    float4v __attribute__((ext_vector_type(4)));

constexpr int PP = 12, DIN = 32, H = 128, HO = 64, DOUT = 3, NL = 3;
constexpr int NB = 4, ROWS = NB * PP;   // 48 rows per block (4 batches x 12)
constexpr int AP2 = 72;                 // AmatT stride (halves)
constexpr int GTS = 136;                // gTT stride (halves): 16B-aligned rows

// ws layout in halves: WinT[128][32] @0 ; WgT[3][128][128] @4096 ; W1T[64][128] @53248
constexpr int WS_WG = 4096, WS_W1 = 53248, WS_TOT = 61440;

__global__ __launch_bounds__(256)
void prep_weights(const float* __restrict__ W_in, const float* __restrict__ W_gcn,
                  const float* __restrict__ W_out1, _Float16* __restrict__ ws)
{
    int e = blockIdx.x * 256 + threadIdx.x;
    if (e < WS_WG) {                        // WinT[n][k] = W_in[k][n]
        int n = e >> 5, k = e & 31;
        ws[e] = (_Float16)W_in[k * H + n];
    } else if (e < WS_W1) {                 // WgT[l][n][k] = W_gcn[l][k][n]
        int e2 = e - WS_WG;
        int l = e2 >> 14, r = e2 & 16383, n = r >> 7, k = r & 127;
        ws[e] = (_Float16)W_gcn[l * (H * H) + k * H + n];
    } else if (e < WS_TOT) {                // W1T[o][k] = W_out1[k][o]
        int e3 = e - WS_W1;
        int o = e3 >> 7, k = e3 & 127;
        ws[e] = (_Float16)W_out1[k * HO + o];
    }
}

__device__ inline half4v pk4(float a, float b, float c, float d) {
    half4v r; r[0] = (_Float16)a; r[1] = (_Float16)b; r[2] = (_Float16)c; r[3] = (_Float16)d;
    return r;
}

__global__ __launch_bounds__(256, 4)
void gnn_mfma(const float* __restrict__ x,
              const float* __restrict__ b_in,
              const float* __restrict__ b_gcn,
              const float* __restrict__ b_out1,
              const float* __restrict__ W_out2,
              const float* __restrict__ b_out2,
              const _Float16* __restrict__ ws,
              float* __restrict__ out)
{
    // h in MFMA fragment layout, single buffer:
    //   hf[mt*4+kt][lane*8+j] = h[16*mt + (lane&15)][32*kt + 8*(lane>>4) + j]
    // t-phase A-frag read = ds_read_b128 at lane*16 (sequential, conflict-free).
    __shared__ __align__(16) _Float16 hf[12][512];     // 12 KB
    __shared__ __align__(16) char r3[ROWS * AP2 * 2];  // 6.75 KB: AmatT, later gTT+ps
    _Float16 (*AmatT)[AP2] = (_Float16 (*)[AP2])r3;
    _Float16* gTT = (_Float16*)r3;                     // [16][GTS] f16 (4352 B used)
    float* psf    = (float*)(r3 + 4608);               // [4 waves][4 b][3 d] fp32

    const int tid  = threadIdx.x;
    const int lane = tid & 63, wave = tid >> 6;
    const int q = lane >> 4, qm = lane & 15;
    const int b0 = blockIdx.x * NB;
    const float* xblk = x + (size_t)b0 * (PP * DIN);
    const _Float16* WgT = ws + WS_WG;

    // ---- issue x loads (lon + proj B-frag quads) ----
    float lon_own = 0.f;
    if (lane < PP) lon_own = xblk[(wave * PP + lane) * DIN];
    float4 xa[3], xb[3];
    #pragma unroll
    for (int nt = 0; nt < 3; ++nt) {
        const float* p = xblk + (16 * nt + qm) * DIN + 8 * q;
        xa[nt] = *(const float4*)p;
        xb[nt] = *(const float4*)(p + 4);
    }

    // ---- adjacency via shfl (bit-exact fp32 mask); wave w = batch w ----
    {
        float lonj[PP];
        #pragma unroll
        for (int j = 0; j < PP; ++j) lonj[j] = __shfl(lon_own, j, 64);
        float deg = 1.0f;                              // GCNConv's appended self-loop
        #pragma unroll
        for (int j = 0; j < PP; ++j) {
            float d = fabsf(lon_own - lonj[j]);
            d = fminf(d, 360.0f - d);
            deg += (d < 10.0f) ? 1.0f : 0.0f;          // diag: d=0 -> 1
        }
        float dinv_own = rsqrtf(fmaxf(deg, 1e-12f));
        float dj[PP];
        #pragma unroll
        for (int j = 0; j < PP; ++j) dj[j] = __shfl(dinv_own, j, 64);

        if (lane < PP) {
            const int n = wave * PP + lane;
            half8v z = {0, 0, 0, 0, 0, 0, 0, 0};
            #pragma unroll
            for (int c = 0; c < 48; c += 8) *(half8v*)&AmatT[n][c] = z;
            _Float16 vals[PP];
            #pragma unroll
            for (int j = 0; j < PP; ++j) {
                float d = fabsf(lon_own - lonj[j]);
                d = fminf(d, 360.0f - d);
                float a = (d < 10.0f) ? 1.0f : 0.0f;
                if (j == lane) a += 1.0f;              // A = mask + eye: diag = 2
                vals[j] = (_Float16)(a * dinv_own * dj[j]);
            }
            #pragma unroll
            for (int t4 = 0; t4 < 3; ++t4) {
                half4v v;
                v[0] = vals[4 * t4]; v[1] = vals[4 * t4 + 1];
                v[2] = vals[4 * t4 + 2]; v[3] = vals[4 * t4 + 3];
                *(half4v*)&AmatT[n][wave * PP + 4 * t4] = v;
            }
        }
    }

    // ---- proj: h0^T = WinT @ x^T -> hf fragment layout ----
    {
        half8v bx[3];
        #pragma unroll
        for (int nt = 0; nt < 3; ++nt) {
            half8v h;
            h[0] = (_Float16)xa[nt].x; h[1] = (_Float16)xa[nt].y;
            h[2] = (_Float16)xa[nt].z; h[3] = (_Float16)xa[nt].w;
            h[4] = (_Float16)xb[nt].x; h[5] = (_Float16)xb[nt].y;
            h[6] = (_Float16)xb[nt].z; h[7] = (_Float16)xb[nt].w;
            bx[nt] = h;
        }
        #pragma unroll
        for (int mt2 = 0; mt2 < 2; ++mt2) {
            const int m = 32 * wave + 16 * mt2;
            half8v aw = *(const half8v*)&ws[(m + qm) * DIN + 8 * q];
            float4 bi = *(const float4*)&b_in[m + 4 * q];
            const int slot = qm + 16 * ((2 * mt2 + (q >> 1)) & 3);
            #pragma unroll
            for (int nt = 0; nt < 3; ++nt) {
                float4v c = {0.f, 0.f, 0.f, 0.f};
                c = __builtin_amdgcn_mfma_f32_16x16x32_f16(aw, bx[nt], c, 0, 0, 0);
                *(half4v*)&hf[nt * 4 + wave][slot * 8 + (q & 1) * 4] =
                    pk4(c[0] + bi.x, c[1] + bi.y, c[2] + bi.z, c[3] + bi.w);
            }
        }
    }

    // ---- layer-0 weight B-frags: issue BEFORE the barrier (latency hidden) ----
    half8v bw[2][4];
    #pragma unroll
    for (int n2 = 0; n2 < 2; ++n2)
        #pragma unroll
        for (int kt = 0; kt < 4; ++kt)
            bw[n2][kt] = *(const half8v*)&WgT[(32 * wave + 16 * n2 + qm) * H + 32 * kt + 8 * q];

    __syncthreads();   // B1: hf + AmatT complete

    // ---- persistent Ahat frags (14 VGPR). bA[mt][nt] = &AmatT[16nt+qm][16mt+4q].
    // Zero tiles (2,0),(0,2) of the block-diagonal Ahat are skipped.
    // As B-frag: B[k=4q+j][col=qm] = Ahat[16nt+col][16mt+k]   (layers 0,1 mix)
    // As A-frag: A[row=qm][k=4q+j] = Ahat[16nt+row][16mt+k]   (layer 2 mix')
    const half4v bA00 = *(const half4v*)&AmatT[qm][4 * q];
    const half4v bA10 = *(const half4v*)&AmatT[qm][16 + 4 * q];
    const half4v bA01 = *(const half4v*)&AmatT[16 + qm][4 * q];
    const half4v bA11 = *(const half4v*)&AmatT[16 + qm][16 + 4 * q];
    const half4v bA21 = *(const half4v*)&AmatT[16 + qm][32 + 4 * q];
    const half4v bA12 = *(const half4v*)&AmatT[32 + qm][16 + 4 * q];
    const half4v bA22 = *(const half4v*)&AmatT[32 + qm][32 + 4 * q];

    #pragma unroll
    for (int l = 0; l < NL; ++l) {
        // t = h @ Wl (K=32 MFMA; A-frags = sequential b128 reads, conflict-free)
        float4v c[3][2];
        #pragma unroll
        for (int mt = 0; mt < 3; ++mt) {
            c[mt][0] = (float4v){0.f, 0.f, 0.f, 0.f};
            c[mt][1] = (float4v){0.f, 0.f, 0.f, 0.f};
        }
        #pragma unroll
        for (int kt = 0; kt < 4; ++kt)
            #pragma unroll
            for (int mt = 0; mt < 3; ++mt) {
                half8v a = *(const half8v*)&hf[mt * 4 + kt][lane * 8];
                c[mt][0] = __builtin_amdgcn_mfma_f32_16x16x32_f16(a, bw[0][kt], c[mt][0], 0, 0, 0);
                c[mt][1] = __builtin_amdgcn_mfma_f32_16x16x32_f16(a, bw[1][kt], c[mt][1], 0, 0, 0);
            }

        // pack t C-tiles -> 16x16x16 frags (chaining identity)
        half4v ah[3][2];
        #pragma unroll
        for (int mt = 0; mt < 3; ++mt)
            #pragma unroll
            for (int n2 = 0; n2 < 2; ++n2)
                ah[mt][n2] = pk4(c[mt][n2][0], c[mt][n2][1], c[mt][n2][2], c[mt][n2][3]);

        if (l < 2) {
            const float4 bg0 = *(const float4*)&b_gcn[l * H + 32 * wave + 4 * q];
            const float4 bg1 = *(const float4*)&b_gcn[l * H + 32 * wave + 16 + 4 * q];
            __syncthreads();   // WAR: all waves done reading hf

            // prefetch next layer's W frags (bw dead; drains at RAW barrier)
            {
                const _Float16* Wn = WgT + (l + 1) * (H * H);
                #pragma unroll
                for (int n2 = 0; n2 < 2; ++n2)
                    #pragma unroll
                    for (int kt = 0; kt < 4; ++kt)
                        bw[n2][kt] = *(const half8v*)&Wn[(32 * wave + 16 * n2 + qm) * H + 32 * kt + 8 * q];
            }

            // mix: h'^T = t^T @ Ahat (ah as A, bA as B); store fragment layout
            #pragma unroll
            for (int n2 = 0; n2 < 2; ++n2) {
                const float4 bg = n2 ? bg1 : bg0;
                const int slot = qm + 16 * ((2 * n2 + (q >> 1)) & 3);
                const int hoff = slot * 8 + (q & 1) * 4;

                float4v d0 = {0.f, 0.f, 0.f, 0.f};
                d0 = __builtin_amdgcn_mfma_f32_16x16x16f16(ah[0][n2], bA00, d0, 0, 0, 0);
                d0 = __builtin_amdgcn_mfma_f32_16x16x16f16(ah[1][n2], bA10, d0, 0, 0, 0);
                *(half4v*)&hf[0 * 4 + wave][hoff] =
                    pk4(fmaxf(d0[0] + bg.x, 0.f), fmaxf(d0[1] + bg.y, 0.f),
                        fmaxf(d0[2] + bg.z, 0.f), fmaxf(d0[3] + bg.w, 0.f));

                float4v d1 = {0.f, 0.f, 0.f, 0.f};
                d1 = __builtin_amdgcn_mfma_f32_16x16x16f16(ah[0][n2], bA01, d1, 0, 0, 0);
                d1 = __builtin_amdgcn_mfma_f32_16x16x16f16(ah[1][n2], bA11, d1, 0, 0, 0);
                d1 = __builtin_amdgcn_mfma_f32_16x16x16f16(ah[2][n2], bA21, d1, 0, 0, 0);
                *(half4v*)&hf[1 * 4 + wave][hoff] =
                    pk4(fmaxf(d1[0] + bg.x, 0.f), fmaxf(d1[1] + bg.y, 0.f),
                        fmaxf(d1[2] + bg.z, 0.f), fmaxf(d1[3] + bg.w, 0.f));

                float4v d2 = {0.f, 0.f, 0.f, 0.f};
                d2 = __builtin_amdgcn_mfma_f32_16x16x16f16(ah[1][n2], bA12, d2, 0, 0, 0);
                d2 = __builtin_amdgcn_mfma_f32_16x16x16f16(ah[2][n2], bA22, d2, 0, 0, 0);
                *(half4v*)&hf[2 * 4 + wave][hoff] =
                    pk4(fmaxf(d2[0] + bg.x, 0.f), fmaxf(d2[1] + bg.y, 0.f),
                        fmaxf(d2[2] + bg.z, 0.f), fmaxf(d2[3] + bg.w, 0.f));
            }
            __syncthreads();   // RAW for next layer
        } else {
            // ---- layer 2: mix' = Ahat @ t (bA as A, ah as B). D[p][c]:
            // lane holds planets 16rt+4q+0..3 (all one batch) for col c=32w+16n2+qm.
            // Bias+ReLU then pool in-lane + 2-step shfl_xor over q.
            float s[3][2];
            #pragma unroll
            for (int n2 = 0; n2 < 2; ++n2) {
                const float bgc = b_gcn[2 * H + 32 * wave + 16 * n2 + qm];
                float4v d;
                d = (float4v){0.f, 0.f, 0.f, 0.f};
                d = __builtin_amdgcn_mfma_f32_16x16x16f16(bA00, ah[0][n2], d, 0, 0, 0);
                d = __builtin_amdgcn_mfma_f32_16x16x16f16(bA10, ah[1][n2], d, 0, 0, 0);
                s[0][n2] = fmaxf(d[0] + bgc, 0.f) + fmaxf(d[1] + bgc, 0.f)
                         + fmaxf(d[2] + bgc, 0.f) + fmaxf(d[3] + bgc, 0.f);
                d = (float4v){0.f, 0.f, 0.f, 0.f};
                d = __builtin_amdgcn_mfma_f32_16x16x16f16(bA01, ah[0][n2], d, 0, 0, 0);
                d = __builtin_amdgcn_mfma_f32_16x16x16f16(bA11, ah[1][n2], d, 0, 0, 0);
                d = __builtin_amdgcn_mfma_f32_16x16x16f16(bA21, ah[2][n2], d, 0, 0, 0);
                s[1][n2] = fmaxf(d[0] + bgc, 0.f) + fmaxf(d[1] + bgc, 0.f)
                         + fmaxf(d[2] + bgc, 0.f) + fmaxf(d[3] + bgc, 0.f);
                d = (float4v){0.f, 0.f, 0.f, 0.f};
                d = __builtin_amdgcn_mfma_f32_16x16x16f16(bA12, ah[1][n2], d, 0, 0, 0);
                d = __builtin_amdgcn_mfma_f32_16x16x16f16(bA22, ah[2][n2], d, 0, 0, 0);
                s[2][n2] = fmaxf(d[0] + bgc, 0.f) + fmaxf(d[1] + bgc, 0.f)
                         + fmaxf(d[2] + bgc, 0.f) + fmaxf(d[3] + bgc, 0.f);
            }
            // batch(rt,q) table: b0:(0,q<=2) b1:(0,3)(1,0)(1,1) b2:(1,2)(1,3)(2,0) b3:(2,q>=1)
            #pragma unroll
            for (int n2 = 0; n2 < 2; ++n2) {
                float g4[4];
                g4[0] = (q <= 2) ? s[0][n2] : 0.f;
                g4[1] = (q == 3) ? s[0][n2] : ((q <= 1) ? s[1][n2] : 0.f);
                g4[2] = (q >= 2) ? s[1][n2] : ((q == 0) ? s[2][n2] : 0.f);
                g4[3] = (q >= 1) ? s[2][n2] : 0.f;
                #pragma unroll
                for (int b = 0; b < 4; ++b) {
                    float v = g4[b];
                    v += __shfl_xor(v, 16, 64);
                    v += __shfl_xor(v, 32, 64);
                    if (q == 0)
                        gTT[b * GTS + 32 * wave + 16 * n2 + qm] =
                            (_Float16)(v * (1.0f / 12.0f));
                }
            }
        }
    }
    __syncthreads();   // gTT complete (aliases dead AmatT; bA lived in regs)

    // ---- out1 via MFMA: o1^T = W1T @ g^T, wave w owns o-tile 16w..16w+15 ----
    float4v acc = {0.f, 0.f, 0.f, 0.f};
    #pragma unroll
    for (int kt = 0; kt < 4; ++kt) {
        half8v aW = *(const half8v*)&ws[WS_W1 + (16 * wave + qm) * H + 32 * kt + 8 * q];
        half8v bG = *(const half8v*)&gTT[qm * GTS + 32 * kt + 8 * q];
        acc = __builtin_amdgcn_mfma_f32_16x16x32_f16(aW, bG, acc, 0, 0, 0);
    }
    // lane holds o1T[o=16w+4q+r][b=qm] (valid qm<4; qm>=4 reads stale small f16s)
    const float4 b1v = *(const float4*)&b_out1[16 * wave + 4 * q];
    float o1v[4];
    o1v[0] = fmaxf(acc[0] + b1v.x, 0.f);
    o1v[1] = fmaxf(acc[1] + b1v.y, 0.f);
    o1v[2] = fmaxf(acc[2] + b1v.z, 0.f);
    o1v[3] = fmaxf(acc[3] + b1v.w, 0.f);
    const float* w2p = W_out2 + (16 * wave + 4 * q) * DOUT;   // 16B-aligned
    const float4 w2a = *(const float4*)(w2p);
    const float4 w2b = *(const float4*)(w2p + 4);
    const float4 w2c = *(const float4*)(w2p + 8);
    float p0 = o1v[0] * w2a.x + o1v[1] * w2a.w + o1v[2] * w2b.z + o1v[3] * w2c.y;
    float p1 = o1v[0] * w2a.y + o1v[1] * w2b.x + o1v[2] * w2b.w + o1v[3] * w2c.z;
    float p2 = o1v[0] * w2a.z + o1v[1] * w2b.y + o1v[2] * w2c.x + o1v[3] * w2c.w;
    p0 += __shfl_xor(p0, 16, 64); p0 += __shfl_xor(p0, 32, 64);
    p1 += __shfl_xor(p1, 16, 64); p1 += __shfl_xor(p1, 32, 64);
    p2 += __shfl_xor(p2, 16, 64); p2 += __shfl_xor(p2, 32, 64);
    if (q == 0 && qm < 4) {
        psf[wave * 12 + qm * 3 + 0] = p0;
        psf[wave * 12 + qm * 3 + 1] = p1;
        psf[wave * 12 + qm * 3 + 2] = p2;
    }
    __syncthreads();
    if (tid < 12) {
        const int b = tid / 3, d = tid - 3 * b;
        const float ssum = psf[b * 3 + d] + psf[12 + b * 3 + d]
                         + psf[24 + b * 3 + d] + psf[36 + b * 3 + d] + b_out2[d];
        out[(size_t)(b0 + b) * DOUT + d] = ssum;
    }
}

extern "C" void kernel_launch(void* const* d_in, const int* in_sizes, int n_in,
                              void* d_out, int out_size, void* d_ws, size_t ws_size,
                              hipStream_t stream) {
    const float* x      = (const float*)d_in[0];
    const float* W_in   = (const float*)d_in[1];
    const float* b_in   = (const float*)d_in[2];
    const float* W_gcn  = (const float*)d_in[3];
    const float* b_gcn  = (const float*)d_in[4];
    const float* W_out1 = (const float*)d_in[5];
    const float* b_out1 = (const float*)d_in[6];
    const float* W_out2 = (const float*)d_in[7];
    const float* b_out2 = (const float*)d_in[8];
    float* outp         = (float*)d_out;
    _Float16* wsh       = (_Float16*)d_ws;

    const int B = in_sizes[0] / (PP * DIN);        // 65536

    hipLaunchKernelGGL(prep_weights, dim3((WS_TOT + 255) / 256), dim3(256), 0, stream,
                       W_in, W_gcn, W_out1, wsh);
    hipLaunchKernelGGL(gnn_mfma, dim3(B / NB), dim3(256), 0, stream,
                       x, b_in, b_gcn, b_out1, W_out2, b_out2, wsh, outp);
}

// Round 3
// 292.526 us; speedup vs baseline: 1.6626x; 1.3619x over previous
//
#include <hip/hip_runtime.h>

// GNNModel fused via MFMA. R15 = R14 + NB=8 via two independent 48-row halves
// (Ahat is block-diagonal per batch): halves share weight-frag loads (aw/bw
// registers serve both), share barriers (2/layer for 2x work), share one
// adjacency pass (width-32 shuffles -> 2 batches/wave/lane-group), and share
// the tail (out1 MFMA B-frag carries 8 batch columns). bA frags reloaded from
// LDS per half per layer (7 b64, latency-hidden) to cap VGPR. Fragment-layout
// hf per half (conflict-free t-phase b128 reads). Adjacency bit-exact fp32.

typedef _Float16 half4v __attribute__((ext_vector_type(4)));
typedef _Float16 half8v __attribute__((ext_vector_type(8)));
typedef float    float4v __attribute__((ext_vector_type(4)));

constexpr int PP = 12, DIN = 32, H = 128, HO = 64, DOUT = 3, NL = 3;
constexpr int NB = 8;                   // 8 batches = two 48-row halves
constexpr int AP2 = 72;                 // Am row stride (halves): 2-way banks only
constexpr int GTS = 136;                // gTT stride (halves)

// ws layout in halves: WinT[128][32] @0 ; WgT[3][128][128] @4096 ; W1T[64][128] @53248
constexpr int WS_WG = 4096, WS_W1 = 53248, WS_TOT = 61440;

__global__ __launch_bounds__(256)
void prep_weights(const float* __restrict__ W_in, const float* __restrict__ W_gcn,
                  const float* __restrict__ W_out1, _Float16* __restrict__ ws)
{
    int e = blockIdx.x * 256 + threadIdx.x;
    if (e < WS_WG) {                        // WinT[n][k] = W_in[k][n]
        int n = e >> 5, k = e & 31;
        ws[e] = (_Float16)W_in[k * H + n];
    } else if (e < WS_W1) {                 // WgT[l][n][k] = W_gcn[l][k][n]
        int e2 = e - WS_WG;
        int l = e2 >> 14, r = e2 & 16383, n = r >> 7, k = r & 127;
        ws[e] = (_Float16)W_gcn[l * (H * H) + k * H + n];
    } else if (e < WS_TOT) {                // W1T[o][k] = W_out1[k][o]
        int e3 = e - WS_W1;
        int o = e3 >> 7, k = e3 & 127;
        ws[e] = (_Float16)W_out1[k * HO + o];
    }
}

__device__ inline half4v pk4(float a, float b, float c, float d) {
    half4v r; r[0] = (_Float16)a; r[1] = (_Float16)b; r[2] = (_Float16)c; r[3] = (_Float16)d;
    return r;
}

__global__ __launch_bounds__(256, 4)
void gnn_mfma(const float* __restrict__ x,
              const float* __restrict__ b_in,
              const float* __restrict__ b_gcn,
              const float* __restrict__ b_out1,
              const float* __restrict__ W_out2,
              const float* __restrict__ b_out2,
              const _Float16* __restrict__ ws,
              float* __restrict__ out)
{
    // Per half h: hf[h][mt*4+kt][lane*8+j] = h[16*mt+(lane&15)][32*kt+8*(lane>>4)+j]
    __shared__ __align__(16) _Float16 hf[2][12][512];   // 24 KB
    __shared__ __align__(16) _Float16 Am[2 * 48 * AP2]; // 13.5 KB (AmatT per half)
    _Float16* gTT = &hf[0][0][0];                       // [8][GTS] alias (post-barrier)
    float*    psf = (float*)&hf[1][0][0];               // [4 waves][8 b][3 d] alias

    const int tid  = threadIdx.x;
    const int lane = tid & 63, wave = tid >> 6;
    const int q = lane >> 4, qm = lane & 15;
    const int hh = lane >> 5, l32 = lane & 31;          // adjacency half / lane-in-half
    const int b0 = blockIdx.x * NB;
    const float* xblk = x + (size_t)b0 * (PP * DIN);
    const _Float16* WgT = ws + WS_WG;

    // ---- lon + half-A x loads (issued early) ----
    float lon_own = 0.f;
    if (l32 < PP) lon_own = xblk[(hh * 48 + wave * PP + l32) * DIN];
    float4 xa[3], xb[3];
    #pragma unroll
    for (int nt = 0; nt < 3; ++nt) {
        const float* p = xblk + (16 * nt + qm) * DIN + 8 * q;
        xa[nt] = *(const float4*)p;
        xb[nt] = *(const float4*)(p + 4);
    }

    // ---- adjacency, BOTH halves in one pass (width-32 shuffles) ----
    {
        float lonj[PP];
        #pragma unroll
        for (int j = 0; j < PP; ++j) lonj[j] = __shfl(lon_own, j, 32);
        float deg = 1.0f;                              // GCNConv's appended self-loop
        #pragma unroll
        for (int j = 0; j < PP; ++j) {
            float d = fabsf(lon_own - lonj[j]);
            d = fminf(d, 360.0f - d);
            deg += (d < 10.0f) ? 1.0f : 0.0f;          // diag: d=0 -> 1
        }
        float dinv_own = rsqrtf(fmaxf(deg, 1e-12f));
        float dj[PP];
        #pragma unroll
        for (int j = 0; j < PP; ++j) dj[j] = __shfl(dinv_own, j, 32);

        if (l32 < PP) {
            _Float16* Ar = Am + (hh * 48 + wave * PP + l32) * AP2;
            half8v z = {0, 0, 0, 0, 0, 0, 0, 0};
            #pragma unroll
            for (int c = 0; c < 48; c += 8) *(half8v*)&Ar[c] = z;
            _Float16 vals[PP];
            #pragma unroll
            for (int j = 0; j < PP; ++j) {
                float d = fabsf(lon_own - lonj[j]);
                d = fminf(d, 360.0f - d);
                float a = (d < 10.0f) ? 1.0f : 0.0f;
                if (j == l32) a += 1.0f;               // A = mask + eye: diag = 2
                vals[j] = (_Float16)(a * dinv_own * dj[j]);
            }
            #pragma unroll
            for (int t4 = 0; t4 < 3; ++t4) {
                half4v v;
                v[0] = vals[4 * t4]; v[1] = vals[4 * t4 + 1];
                v[2] = vals[4 * t4 + 2]; v[3] = vals[4 * t4 + 3];
                *(half4v*)&Ar[wave * PP + 4 * t4] = v;
            }
        }
    }

    // ---- pack half-A x, then issue half-B x loads (latency under proj-A) ----
    half8v bxA[3];
    #pragma unroll
    for (int nt = 0; nt < 3; ++nt) {
        half8v h;
        h[0] = (_Float16)xa[nt].x; h[1] = (_Float16)xa[nt].y;
        h[2] = (_Float16)xa[nt].z; h[3] = (_Float16)xa[nt].w;
        h[4] = (_Float16)xb[nt].x; h[5] = (_Float16)xb[nt].y;
        h[6] = (_Float16)xb[nt].z; h[7] = (_Float16)xb[nt].w;
        bxA[nt] = h;
    }
    #pragma unroll
    for (int nt = 0; nt < 3; ++nt) {
        const float* p = xblk + (48 + 16 * nt + qm) * DIN + 8 * q;
        xa[nt] = *(const float4*)p;
        xb[nt] = *(const float4*)(p + 4);
    }

    // ---- proj: both halves share the SAME aw/bias registers ----
    {
        const int m0 = 32 * wave, m1 = 32 * wave + 16;
        half8v aw0 = *(const half8v*)&ws[(m0 + qm) * DIN + 8 * q];
        half8v aw1 = *(const half8v*)&ws[(m1 + qm) * DIN + 8 * q];
        float4 bi0 = *(const float4*)&b_in[m0 + 4 * q];
        float4 bi1 = *(const float4*)&b_in[m1 + 4 * q];
        const int ho0 = (qm + 16 * ((q >> 1) & 3)) * 8 + (q & 1) * 4;        // mt2=0
        const int ho1 = (qm + 16 * ((2 + (q >> 1)) & 3)) * 8 + (q & 1) * 4;  // mt2=1
        #pragma unroll
        for (int nt = 0; nt < 3; ++nt) {
            float4v c0 = {0.f, 0.f, 0.f, 0.f}, c1 = {0.f, 0.f, 0.f, 0.f};
            c0 = __builtin_amdgcn_mfma_f32_16x16x32_f16(aw0, bxA[nt], c0, 0, 0, 0);
            c1 = __builtin_amdgcn_mfma_f32_16x16x32_f16(aw1, bxA[nt], c1, 0, 0, 0);
            *(half4v*)&hf[0][nt * 4 + wave][ho0] =
                pk4(c0[0] + bi0.x, c0[1] + bi0.y, c0[2] + bi0.z, c0[3] + bi0.w);
            *(half4v*)&hf[0][nt * 4 + wave][ho1] =
                pk4(c1[0] + bi1.x, c1[1] + bi1.y, c1[2] + bi1.z, c1[3] + bi1.w);
        }
        half8v bxB[3];
        #pragma unroll
        for (int nt = 0; nt < 3; ++nt) {
            half8v h;
            h[0] = (_Float16)xa[nt].x; h[1] = (_Float16)xa[nt].y;
            h[2] = (_Float16)xa[nt].z; h[3] = (_Float16)xa[nt].w;
            h[4] = (_Float16)xb[nt].x; h[5] = (_Float16)xb[nt].y;
            h[6] = (_Float16)xb[nt].z; h[7] = (_Float16)xb[nt].w;
            bxB[nt] = h;
        }
        #pragma unroll
        for (int nt = 0; nt < 3; ++nt) {
            float4v c0 = {0.f, 0.f, 0.f, 0.f}, c1 = {0.f, 0.f, 0.f, 0.f};
            c0 = __builtin_amdgcn_mfma_f32_16x16x32_f16(aw0, bxB[nt], c0, 0, 0, 0);
            c1 = __builtin_amdgcn_mfma_f32_16x16x32_f16(aw1, bxB[nt], c1, 0, 0, 0);
            *(half4v*)&hf[1][nt * 4 + wave][ho0] =
                pk4(c0[0] + bi0.x, c0[1] + bi0.y, c0[2] + bi0.z, c0[3] + bi0.w);
            *(half4v*)&hf[1][nt * 4 + wave][ho1] =
                pk4(c1[0] + bi1.x, c1[1] + bi1.y, c1[2] + bi1.z, c1[3] + bi1.w);
        }
    }

    // ---- layer-0 weight B-frags: issue BEFORE the barrier (latency hidden) ----
    half8v bw[2][4];
    #pragma unroll
    for (int n2 = 0; n2 < 2; ++n2)
        #pragma unroll
        for (int kt = 0; kt < 4; ++kt)
            bw[n2][kt] = *(const half8v*)&WgT[(32 * wave + 16 * n2 + qm) * H + 32 * kt + 8 * q];

    __syncthreads();   // B1: hf (both halves) + Am complete

    #pragma unroll
    for (int l = 0; l < NL; ++l) {
        // t = h @ Wl for both halves, SHARED bw registers (all-static indexing)
        half4v ah[2][3][2];
        #pragma unroll
        for (int h = 0; h < 2; ++h) {
            float4v c[3][2];
            #pragma unroll
            for (int mt = 0; mt < 3; ++mt) {
                c[mt][0] = (float4v){0.f, 0.f, 0.f, 0.f};
                c[mt][1] = (float4v){0.f, 0.f, 0.f, 0.f};
            }
            #pragma unroll
            for (int kt = 0; kt < 4; ++kt)
                #pragma unroll
                for (int mt = 0; mt < 3; ++mt) {
                    half8v a = *(const half8v*)&hf[h][mt * 4 + kt][lane * 8];
                    c[mt][0] = __builtin_amdgcn_mfma_f32_16x16x32_f16(a, bw[0][kt], c[mt][0], 0, 0, 0);
                    c[mt][1] = __builtin_amdgcn_mfma_f32_16x16x32_f16(a, bw[1][kt], c[mt][1], 0, 0, 0);
                }
            #pragma unroll
            for (int mt = 0; mt < 3; ++mt)
                #pragma unroll
                for (int n2 = 0; n2 < 2; ++n2)
                    ah[h][mt][n2] = pk4(c[mt][n2][0], c[mt][n2][1], c[mt][n2][2], c[mt][n2][3]);
        }

        if (l < 2) {
            const float4 bg0 = *(const float4*)&b_gcn[l * H + 32 * wave + 4 * q];
            const float4 bg1 = *(const float4*)&b_gcn[l * H + 32 * wave + 16 + 4 * q];
            __syncthreads();   // WAR: all waves done reading hf (both halves)

            // prefetch next layer's W frags (bw dead; drains at RAW barrier)
            {
                const _Float16* Wn = WgT + (l + 1) * (H * H);
                #pragma unroll
                for (int n2 = 0; n2 < 2; ++n2)
                    #pragma unroll
                    for (int kt = 0; kt < 4; ++kt)
                        bw[n2][kt] = *(const half8v*)&Wn[(32 * wave + 16 * n2 + qm) * H + 32 * kt + 8 * q];
            }

            // mix per half: h'^T = t^T @ Ahat_h (bA from LDS, 7 b64, 2-way banks)
            #pragma unroll
            for (int h = 0; h < 2; ++h) {
                const _Float16* Ah = Am + h * 48 * AP2;
                const half4v bA00 = *(const half4v*)&Ah[qm * AP2 + 4 * q];
                const half4v bA10 = *(const half4v*)&Ah[qm * AP2 + 16 + 4 * q];
                const half4v bA01 = *(const half4v*)&Ah[(16 + qm) * AP2 + 4 * q];
                const half4v bA11 = *(const half4v*)&Ah[(16 + qm) * AP2 + 16 + 4 * q];
                const half4v bA21 = *(const half4v*)&Ah[(16 + qm) * AP2 + 32 + 4 * q];
                const half4v bA12 = *(const half4v*)&Ah[(32 + qm) * AP2 + 16 + 4 * q];
                const half4v bA22 = *(const half4v*)&Ah[(32 + qm) * AP2 + 32 + 4 * q];
                #pragma unroll
                for (int n2 = 0; n2 < 2; ++n2) {
                    const float4 bg = n2 ? bg1 : bg0;
                    const int hoff = (qm + 16 * ((2 * n2 + (q >> 1)) & 3)) * 8 + (q & 1) * 4;

                    float4v d0 = {0.f, 0.f, 0.f, 0.f};
                    d0 = __builtin_amdgcn_mfma_f32_16x16x16f16(ah[h][0][n2], bA00, d0, 0, 0, 0);
                    d0 = __builtin_amdgcn_mfma_f32_16x16x16f16(ah[h][1][n2], bA10, d0, 0, 0, 0);
                    *(half4v*)&hf[h][0 * 4 + wave][hoff] =
                        pk4(fmaxf(d0[0] + bg.x, 0.f), fmaxf(d0[1] + bg.y, 0.f),
                            fmaxf(d0[2] + bg.z, 0.f), fmaxf(d0[3] + bg.w, 0.f));

                    float4v d1 = {0.f, 0.f, 0.f, 0.f};
                    d1 = __builtin_amdgcn_mfma_f32_16x16x16f16(ah[h][0][n2], bA01, d1, 0, 0, 0);
                    d1 = __builtin_amdgcn_mfma_f32_16x16x16f16(ah[h][1][n2], bA11, d1, 0, 0, 0);
                    d1 = __builtin_amdgcn_mfma_f32_16x16x16f16(ah[h][2][n2], bA21, d1, 0, 0, 0);
                    *(half4v*)&hf[h][1 * 4 + wave][hoff] =
                        pk4(fmaxf(d1[0] + bg.x, 0.f), fmaxf(d1[1] + bg.y, 0.f),
                            fmaxf(d1[2] + bg.z, 0.f), fmaxf(d1[3] + bg.w, 0.f));

                    float4v d2 = {0.f, 0.f, 0.f, 0.f};
                    d2 = __builtin_amdgcn_mfma_f32_16x16x16f16(ah[h][1][n2], bA12, d2, 0, 0, 0);
                    d2 = __builtin_amdgcn_mfma_f32_16x16x16f16(ah[h][2][n2], bA22, d2, 0, 0, 0);
                    *(half4v*)&hf[h][2 * 4 + wave][hoff] =
                        pk4(fmaxf(d2[0] + bg.x, 0.f), fmaxf(d2[1] + bg.y, 0.f),
                            fmaxf(d2[2] + bg.z, 0.f), fmaxf(d2[3] + bg.w, 0.f));
                }
            }
            __syncthreads();   // RAW for next layer
        } else {
            // ---- layer 2: mix' = Ahat @ t per half; pool in-lane + shfl_xor.
            __syncthreads();   // all hf reads done -> gTT/psf alias of hf is safe
            const float bgc0 = b_gcn[2 * H + 32 * wave + qm];
            const float bgc1 = b_gcn[2 * H + 32 * wave + 16 + qm];
            #pragma unroll
            for (int h = 0; h < 2; ++h) {
                const _Float16* Ah = Am + h * 48 * AP2;
                const half4v bA00 = *(const half4v*)&Ah[qm * AP2 + 4 * q];
                const half4v bA10 = *(const half4v*)&Ah[qm * AP2 + 16 + 4 * q];
                const half4v bA01 = *(const half4v*)&Ah[(16 + qm) * AP2 + 4 * q];
                const half4v bA11 = *(const half4v*)&Ah[(16 + qm) * AP2 + 16 + 4 * q];
                const half4v bA21 = *(const half4v*)&Ah[(16 + qm) * AP2 + 32 + 4 * q];
                const half4v bA12 = *(const half4v*)&Ah[(32 + qm) * AP2 + 16 + 4 * q];
                const half4v bA22 = *(const half4v*)&Ah[(32 + qm) * AP2 + 32 + 4 * q];
                float s[3][2];
                #pragma unroll
                for (int n2 = 0; n2 < 2; ++n2) {
                    const float bgc = n2 ? bgc1 : bgc0;
                    float4v d;
                    d = (float4v){0.f, 0.f, 0.f, 0.f};
                    d = __builtin_amdgcn_mfma_f32_16x16x16f16(bA00, ah[h][0][n2], d, 0, 0, 0);
                    d = __builtin_amdgcn_mfma_f32_16x16x16f16(bA10, ah[h][1][n2], d, 0, 0, 0);
                    s[0][n2] = fmaxf(d[0] + bgc, 0.f) + fmaxf(d[1] + bgc, 0.f)
                             + fmaxf(d[2] + bgc, 0.f) + fmaxf(d[3] + bgc, 0.f);
                    d = (float4v){0.f, 0.f, 0.f, 0.f};
                    d = __builtin_amdgcn_mfma_f32_16x16x16f16(bA01, ah[h][0][n2], d, 0, 0, 0);
                    d = __builtin_amdgcn_mfma_f32_16x16x16f16(bA11, ah[h][1][n2], d, 0, 0, 0);
                    d = __builtin_amdgcn_mfma_f32_16x16x16f16(bA21, ah[h][2][n2], d, 0, 0, 0);
                    s[1][n2] = fmaxf(d[0] + bgc, 0.f) + fmaxf(d[1] + bgc, 0.f)
                             + fmaxf(d[2] + bgc, 0.f) + fmaxf(d[3] + bgc, 0.f);
                    d = (float4v){0.f, 0.f, 0.f, 0.f};
                    d = __builtin_amdgcn_mfma_f32_16x16x16f16(bA12, ah[h][1][n2], d, 0, 0, 0);
                    d = __builtin_amdgcn_mfma_f32_16x16x16f16(bA22, ah[h][2][n2], d, 0, 0, 0);
                    s[2][n2] = fmaxf(d[0] + bgc, 0.f) + fmaxf(d[1] + bgc, 0.f)
                             + fmaxf(d[2] + bgc, 0.f) + fmaxf(d[3] + bgc, 0.f);
                }
                // batch(rt,q): b0:(0,q<=2) b1:(0,3)(1,0)(1,1) b2:(1,2)(1,3)(2,0) b3:(2,q>=1)
                #pragma unroll
                for (int n2 = 0; n2 < 2; ++n2) {
                    float g4[4];
                    g4[0] = (q <= 2) ? s[0][n2] : 0.f;
                    g4[1] = (q == 3) ? s[0][n2] : ((q <= 1) ? s[1][n2] : 0.f);
                    g4[2] = (q >= 2) ? s[1][n2] : ((q == 0) ? s[2][n2] : 0.f);
                    g4[3] = (q >= 1) ? s[2][n2] : 0.f;
                    #pragma unroll
                    for (int b = 0; b < 4; ++b) {
                        float v = g4[b];
                        v += __shfl_xor(v, 16, 64);
                        v += __shfl_xor(v, 32, 64);
                        if (q == 0)
                            gTT[(4 * h + b) * GTS + 32 * wave + 16 * n2 + qm] =
                                (_Float16)(v * (1.0f / 12.0f));
                    }
                }
            }
            __syncthreads();   // gTT complete
        }
    }

    // ---- out1 via MFMA: o1^T = W1T @ g^T; B-frag cols = 8 batches ----
    float4v acc = {0.f, 0.f, 0.f, 0.f};
    #pragma unroll
    for (int kt = 0; kt < 4; ++kt) {
        half8v aW = *(const half8v*)&ws[WS_W1 + (16 * wave + qm) * H + 32 * kt + 8 * q];
        half8v bG = *(const half8v*)&gTT[qm * GTS + 32 * kt + 8 * q];
        acc = __builtin_amdgcn_mfma_f32_16x16x32_f16(aW, bG, acc, 0, 0, 0);
    }
    // lane holds o1T[o=16w+4q+r][b=qm] (valid qm<8; qm>=8 garbage, discarded)
    const float4 b1v = *(const float4*)&b_out1[16 * wave + 4 * q];
    float o1v[4];
    o1v[0] = fmaxf(acc[0] + b1v.x, 0.f);
    o1v[1] = fmaxf(acc[1] + b1v.y, 0.f);
    o1v[2] = fmaxf(acc[2] + b1v.z, 0.f);
    o1v[3] = fmaxf(acc[3] + b1v.w, 0.f);
    const float* w2p = W_out2 + (16 * wave + 4 * q) * DOUT;   // 16B-aligned
    const float4 w2a = *(const float4*)(w2p);
    const float4 w2b = *(const float4*)(w2p + 4);
    const float4 w2c = *(const float4*)(w2p + 8);
    float p0 = o1v[0] * w2a.x + o1v[1] * w2a.w + o1v[2] * w2b.z + o1v[3] * w2c.y;
    float p1 = o1v[0] * w2a.y + o1v[1] * w2b.x + o1v[2] * w2b.w + o1v[3] * w2c.z;
    float p2 = o1v[0] * w2a.z + o1v[1] * w2b.y + o1v[2] * w2c.x + o1v[3] * w2c.w;
    p0 += __shfl_xor(p0, 16, 64); p0 += __shfl_xor(p0, 32, 64);
    p1 += __shfl_xor(p1, 16, 64); p1 += __shfl_xor(p1, 32, 64);
    p2 += __shfl_xor(p2, 16, 64); p2 += __shfl_xor(p2, 32, 64);
    if (q == 0 && qm < NB) {
        psf[wave * (NB * DOUT) + qm * DOUT + 0] = p0;
        psf[wave * (NB * DOUT) + qm * DOUT + 1] = p1;
        psf[wave * (NB * DOUT) + qm * DOUT + 2] = p2;
    }
    __syncthreads();
    if (tid < NB * DOUT) {   // 24
        const int b = tid / 3, d = tid - 3 * b;
        const float ssum = psf[b * 3 + d] + psf[24 + b * 3 + d]
                         + psf[48 + b * 3 + d] + psf[72 + b * 3 + d] + b_out2[d];
        out[(size_t)(b0 + b) * DOUT + d] = ssum;
    }
}

extern "C" void kernel_launch(void* const* d_in, const int* in_sizes, int n_in,
                              void* d_out, int out_size, void* d_ws, size_t ws_size,
                              hipStream_t stream) {
    const float* x      = (const float*)d_in[0];
    const float* W_in   = (const float*)d_in[1];
    const float* b_in   = (const float*)d_in[2];
    const float* W_gcn  = (const float*)d_in[3];
    const float* b_gcn  = (const float*)d_in[4];
    const float* W_out1 = (const float*)d_in[5];
    const float* b_out1 = (const float*)d_in[6];
    const float* W_out2 = (const float*)d_in[7];
    const float* b_out2 = (const float*)d_in[8];
    float* outp         = (float*)d_out;
    _Float16* wsh       = (_Float16*)d_ws;

    const int B = in_sizes[0] / (PP * DIN);        // 65536

    hipLaunchKernelGGL(prep_weights, dim3((WS_TOT + 255) / 256), dim3(256), 0, stream,
                       W_in, W_gcn, W_out1, wsh);
    hipLaunchKernelGGL(gnn_mfma, dim3(B / NB), dim3(256), 0, stream,
                       x, b_in, b_gcn, b_out1, W_out2, b_out2, wsh, outp);
}